// Round 20
// baseline (5448.503 us; speedup 1.0000x reference)
//
#include <hip/hip_runtime.h>
#include <math.h>

#define B_ROWS 32768
#define DIM    1024
#define PADA   268   // A LDS stride (256 cols + shift<=4 + pad); 268 mod 32 = 12
#define PADB   140   // B LDS stride (128 cols + shift<=4 + pad); 140 mod 32 = 12

// Numerics contract (verified r10-r19, absmax 0.0): BLIS sgemm, KC=512.
// Per C element: p1 = serial ascending FMA chain k=0..511, p2 = k=512..1023,
// C = fl(p1+p2). Split-K: *_part kernels compute p1 -> partial buffer (the
// sgn output region, scratch until k5_final); *_final kernels compute p2,
// fold fl(p1+p2), run the epilogue.
//
// r19->r20: same 16x8 tile / 256x128 block / split-K; change = LDS DOUBLE
// BUFFER (BK=16, two 26KB buffers): one barrier per chunk, stores overlap
// the other buffer's compute -> staging off the critical path.
// Banks: strides ≡12 mod 32, shift col' = col + 4*(krow>>3):
// writes <=2-way, A reads broadcast, B reads 2-way — all free (m136).

struct Frag16  { float4 a[4]; float4 b[2]; };
struct FragG16 { uchar4 a[4]; float4 b[2]; };

__device__ __forceinline__ void load16(const float* pA, const float* pB, Frag16& f) {
#pragma unroll
    for (int i = 0; i < 4; ++i) f.a[i] = *(const float4*)(pA + (size_t)(64 * i) * DIM);
#pragma unroll
    for (int i = 0; i < 2; ++i) f.b[i] = *(const float4*)(pB + (size_t)(64 * i) * DIM);
}

__device__ __forceinline__ void store16(const Frag16& f, float (*As)[PADA], float (*Bs)[PADB],
                                        int kq, int r) {
    const int c0 = kq * 4, sh = 4 * (kq >> 1);   // sh = 4*((4kq+j)>>3), j<4
#pragma unroll
    for (int i = 0; i < 4; ++i) {
        const int col = r + 64 * i + sh;
        As[c0 + 0][col] = f.a[i].x; As[c0 + 1][col] = f.a[i].y;
        As[c0 + 2][col] = f.a[i].z; As[c0 + 3][col] = f.a[i].w;
    }
#pragma unroll
    for (int i = 0; i < 2; ++i) {
        const int col = r + 64 * i + sh;
        Bs[c0 + 0][col] = f.b[i].x; Bs[c0 + 1][col] = f.b[i].y;
        Bs[c0 + 2][col] = f.b[i].z; Bs[c0 + 3][col] = f.b[i].w;
    }
}

__device__ __forceinline__ void compute16(const float (*As)[PADA], const float (*Bs)[PADB],
                                          int tx, int ty, float (&acc)[16][8]) {
#pragma unroll
    for (int kk = 0; kk < 16; ++kk) {
        const int sh = 4 * (kk >> 3);            // compile-time per unrolled kk
        const float4 A0 = *(const float4*)&As[kk][4 * ty + sh];
        const float4 A1 = *(const float4*)&As[kk][4 * ty + 64 + sh];
        const float4 A2 = *(const float4*)&As[kk][4 * ty + 128 + sh];
        const float4 A3 = *(const float4*)&As[kk][4 * ty + 192 + sh];
        const float4 B0 = *(const float4*)&Bs[kk][4 * tx + sh];
        const float4 B1 = *(const float4*)&Bs[kk][4 * tx + 64 + sh];
        const float a[16] = {A0.x, A0.y, A0.z, A0.w, A1.x, A1.y, A1.z, A1.w,
                             A2.x, A2.y, A2.z, A2.w, A3.x, A3.y, A3.z, A3.w};
        const float b[8]  = {B0.x, B0.y, B0.z, B0.w, B1.x, B1.y, B1.z, B1.w};
#pragma unroll
        for (int i = 0; i < 16; ++i)
#pragma unroll
            for (int j = 0; j < 8; ++j)
                acc[i][j] = fmaf(a[i], b[j], acc[i][j]);
    }
}

// ---- double-buffered K-half loop, A@B^T form (A,B row-major [rows][k]) ----
__device__ __forceinline__ void runT16(const float* Ab, const float* Bb, int m0, int n0,
                                       int koff, int tid,
                                       float (*As0)[PADA], float (*Bs0)[PADB],
                                       float (*As1)[PADA], float (*Bs1)[PADB],
                                       float (&acc)[16][8]) {
    const int tx = tid & 15, ty = tid >> 4, kq = tid & 3, r = tid >> 2;
    const float* pA = Ab + (size_t)(m0 + r) * DIM + koff + kq * 4;
    const float* pB = Bb + (size_t)(n0 + r) * DIM + koff + kq * 4;
    Frag16 f;
    load16(pA, pB, f);
    store16(f, As0, Bs0, kq, r);
    for (int c = 0; c < 32; c += 2) {
        __syncthreads();
        load16(pA + (c + 1) * 16, pB + (c + 1) * 16, f);       // c+1 <= 31 always
        compute16(As0, Bs0, tx, ty, acc);
        store16(f, As1, Bs1, kq, r);
        __syncthreads();
        if (c < 30) load16(pA + (c + 2) * 16, pB + (c + 2) * 16, f);
        compute16(As1, Bs1, tx, ty, acc);
        if (c < 30) store16(f, As0, Bs0, kq, r);
    }
}

// ---- double-buffered K-half loop, gather-A (centroids) @ Pi ([k][n]) ----
__device__ __forceinline__ void runG16(const unsigned char* idxb, const float* Pi,
                                       const float* clut, int m0, int n0, int koff, int tid,
                                       float (*As0)[PADA], float (*Bs0)[PADB],
                                       float (*As1)[PADA], float (*Bs1)[PADB],
                                       float (&acc)[16][8]) {
    const int tx = tid & 15, ty = tid >> 4, kq = tid & 3, r = tid >> 2;
    const int nq = tid & 31, kr = tid >> 5;                    // B map: 16k x 128n
    const unsigned char* pA = idxb + (size_t)(m0 + r) * DIM + koff + kq * 4;
    const float*         pB = Pi + (size_t)(koff + kr) * DIM + n0 + nq * 4;
    FragG16 f;
#pragma unroll
    for (int i = 0; i < 4; ++i) f.a[i] = *(const uchar4*)(pA + (size_t)(64 * i) * DIM);
#pragma unroll
    for (int i = 0; i < 2; ++i) f.b[i] = *(const float4*)(pB + (size_t)(8 * i) * DIM);
#define STORE_G(As, Bs)                                                          \
    {   const int c0 = kq * 4, sh = 4 * (kq >> 1);                               \
        _Pragma("unroll")                                                        \
        for (int i = 0; i < 4; ++i) {                                            \
            const int col = r + 64 * i + sh;                                     \
            As[c0 + 0][col] = clut[f.a[i].x]; As[c0 + 1][col] = clut[f.a[i].y];  \
            As[c0 + 2][col] = clut[f.a[i].z]; As[c0 + 3][col] = clut[f.a[i].w];  \
        }                                                                        \
        _Pragma("unroll")                                                        \
        for (int i = 0; i < 2; ++i)                                              \
            *(float4*)&Bs[kr + 8 * i][nq * 4 + 4 * i] = f.b[i];                  \
    }
#define LOAD_G(cc)                                                               \
    {   _Pragma("unroll")                                                        \
        for (int i = 0; i < 4; ++i)                                              \
            f.a[i] = *(const uchar4*)(pA + (cc) * 16 + (size_t)(64 * i) * DIM);  \
        _Pragma("unroll")                                                        \
        for (int i = 0; i < 2; ++i)                                              \
            f.b[i] = *(const float4*)(pB + (size_t)((cc) * 16 + 8 * i) * DIM);   \
    }
    STORE_G(As0, Bs0);
    for (int c = 0; c < 32; c += 2) {
        __syncthreads();
        LOAD_G(c + 1);
        compute16(As0, Bs0, tx, ty, acc);
        STORE_G(As1, Bs1);
        __syncthreads();
        if (c < 30) LOAD_G(c + 2);
        compute16(As1, Bs1, tx, ty, acc);
        if (c < 30) STORE_G(As0, Bs0);
    }
#undef STORE_G
#undef LOAD_G
}

// ---------------- kT_part: partial p1 (k<512), A@B^T -> part ----------------
__global__ __launch_bounds__(256) void kT_part(
    const float* __restrict__ A, const float* __restrict__ B, float* __restrict__ part)
{
    __shared__ float As0[16][PADA], Bs0[16][PADB], As1[16][PADA], Bs1[16][PADB];
    const int tid = threadIdx.x, tx = tid & 15, ty = tid >> 4;
    const int m0 = blockIdx.y * 256, n0 = blockIdx.x * 128;
    float acc[16][8] = {};
    runT16(A, B, m0, n0, 0, tid, As0, Bs0, As1, Bs1, acc);
#pragma unroll
    for (int i = 0; i < 16; ++i) {
        const int row = m0 + 64 * (i >> 2) + 4 * ty + (i & 3);
        const size_t o = (size_t)row * DIM + n0 + tx * 4;
        *(float4*)&part[o]      = make_float4(acc[i][0], acc[i][1], acc[i][2], acc[i][3]);
        *(float4*)&part[o + 64] = make_float4(acc[i][4], acc[i][5], acc[i][6], acc[i][7]);
    }
}

// ---------------- k1_final: p2 + fold + argmin -> idxf, idx8 ----------------
__global__ __launch_bounds__(256) void k1_final(
    const float* __restrict__ X, const float* __restrict__ Pi, const float* __restrict__ C,
    const float* __restrict__ part, float* __restrict__ idxf, unsigned char* __restrict__ idx8)
{
    __shared__ float As0[16][PADA], Bs0[16][PADB], As1[16][PADA], Bs1[16][PADB];
    const int tid = threadIdx.x, tx = tid & 15, ty = tid >> 4;
    const int m0 = blockIdx.y * 256, n0 = blockIdx.x * 128;
    float acc[16][8] = {};
    runT16(X, Pi, m0, n0, 512, tid, As0, Bs0, As1, Bs1, acc);
    float c8[8];
#pragma unroll
    for (int t = 0; t < 8; ++t) c8[t] = C[t];
#pragma unroll
    for (int i = 0; i < 16; ++i) {
        const int row = m0 + 64 * (i >> 2) + 4 * ty + (i & 3);
        const size_t o = (size_t)row * DIM + n0 + tx * 4;
        const float4 p1l = *(const float4*)&part[o];
        const float4 p1h = *(const float4*)&part[o + 64];
        const float y[8] = {p1l.x + acc[i][0], p1l.y + acc[i][1], p1l.z + acc[i][2], p1l.w + acc[i][3],
                            p1h.x + acc[i][4], p1h.y + acc[i][5], p1h.z + acc[i][6], p1h.w + acc[i][7]};
        float fv[8]; unsigned char bv[8];
#pragma unroll
        for (int j = 0; j < 8; ++j) {
            float best = fabsf(y[j] - c8[0]); int bi = 0;
#pragma unroll
            for (int t2 = 1; t2 < 8; ++t2) {
                const float d = fabsf(y[j] - c8[t2]);
                if (d < best) { best = d; bi = t2; }   // strict <: np first-min tie rule
            }
            fv[j] = (float)bi; bv[j] = (unsigned char)bi;
        }
        *(float4*)&idxf[o]      = make_float4(fv[0], fv[1], fv[2], fv[3]);
        *(float4*)&idxf[o + 64] = make_float4(fv[4], fv[5], fv[6], fv[7]);
        *(uchar4*)&idx8[o]      = make_uchar4(bv[0], bv[1], bv[2], bv[3]);
        *(uchar4*)&idx8[o + 64] = make_uchar4(bv[4], bv[5], bv[6], bv[7]);
    }
}

// ---------------- k3_part: partial p1 of xhat = yhat @ Pi ----------------
__global__ __launch_bounds__(256) void k3_part(
    const unsigned char* __restrict__ idx8, const float* __restrict__ Pi,
    const float* __restrict__ C, float* __restrict__ part)
{
    __shared__ float As0[16][PADA], Bs0[16][PADB], As1[16][PADA], Bs1[16][PADB];
    __shared__ float clut[8];
    const int tid = threadIdx.x, tx = tid & 15, ty = tid >> 4;
    const int m0 = blockIdx.y * 256, n0 = blockIdx.x * 128;
    if (tid < 8) clut[tid] = C[tid];
    __syncthreads();                               // clut visible before first gather-store
    float acc[16][8] = {};
    runG16(idx8, Pi, clut, m0, n0, 0, tid, As0, Bs0, As1, Bs1, acc);
#pragma unroll
    for (int i = 0; i < 16; ++i) {
        const int row = m0 + 64 * (i >> 2) + 4 * ty + (i & 3);
        const size_t o = (size_t)row * DIM + n0 + tx * 4;
        *(float4*)&part[o]      = make_float4(acc[i][0], acc[i][1], acc[i][2], acc[i][3]);
        *(float4*)&part[o + 64] = make_float4(acc[i][4], acc[i][5], acc[i][6], acc[i][7]);
    }
}

// ---------------- k3_final: p2 + fold; R = X - xhat; norm partials ----------------
__global__ __launch_bounds__(256) void k3_final(
    const float* __restrict__ X, const float* __restrict__ Pi, const float* __restrict__ C,
    const unsigned char* __restrict__ idx8, const float* __restrict__ part,
    float* __restrict__ R, double* __restrict__ nrm2)
{
    __shared__ float As0[16][PADA], Bs0[16][PADB], As1[16][PADA], Bs1[16][PADB];
    __shared__ float clut[8];
    const int tid = threadIdx.x, tx = tid & 15, ty = tid >> 4;
    const int m0 = blockIdx.y * 256, n0 = blockIdx.x * 128;
    if (tid < 8) clut[tid] = C[tid];
    __syncthreads();
    float acc[16][8] = {};
    runG16(idx8, Pi, clut, m0, n0, 512, tid, As0, Bs0, As1, Bs1, acc);
#pragma unroll
    for (int i = 0; i < 16; ++i) {
        const int row = m0 + 64 * (i >> 2) + 4 * ty + (i & 3);
        const size_t o = (size_t)row * DIM + n0 + tx * 4;
        const float4 p1l = *(const float4*)&part[o];
        const float4 p1h = *(const float4*)&part[o + 64];
        const float4 x0 = *(const float4*)&X[o];
        const float4 x1 = *(const float4*)&X[o + 64];
        float rv[8];
        rv[0] = x0.x - (p1l.x + acc[i][0]); rv[1] = x0.y - (p1l.y + acc[i][1]);
        rv[2] = x0.z - (p1l.z + acc[i][2]); rv[3] = x0.w - (p1l.w + acc[i][3]);
        rv[4] = x1.x - (p1h.x + acc[i][4]); rv[5] = x1.y - (p1h.y + acc[i][5]);
        rv[6] = x1.z - (p1h.z + acc[i][6]); rv[7] = x1.w - (p1h.w + acc[i][7]);
        *(float4*)&R[o]      = make_float4(rv[0], rv[1], rv[2], rv[3]);
        *(float4*)&R[o + 64] = make_float4(rv[4], rv[5], rv[6], rv[7]);
        double s = 0.0;
#pragma unroll
        for (int j = 0; j < 8; ++j) s = fma((double)rv[j], (double)rv[j], s);
#pragma unroll
        for (int mask = 1; mask < 16; mask <<= 1) s += __shfl_xor(s, mask, 16);
        if (tx == 0) atomicAdd(&nrm2[row], s);
    }
}

// ---------------- k5_final: p2 + fold + sign (partial lives in SAME buffer) ----------------
__global__ __launch_bounds__(256) void k5_final(
    const float* __restrict__ R, const float* __restrict__ S, float* psgn)
{
    __shared__ float As0[16][PADA], Bs0[16][PADB], As1[16][PADA], Bs1[16][PADB];
    const int tid = threadIdx.x, tx = tid & 15, ty = tid >> 4;
    const int m0 = blockIdx.y * 256, n0 = blockIdx.x * 128;
    float acc[16][8] = {};
    runT16(R, S, m0, n0, 512, tid, As0, Bs0, As1, Bs1, acc);
#pragma unroll
    for (int i = 0; i < 16; ++i) {
        const int row = m0 + 64 * (i >> 2) + 4 * ty + (i & 3);
        const size_t o = (size_t)row * DIM + n0 + tx * 4;
        const float4 p1l = *(const float4*)&psgn[o];       // read partial
        const float4 p1h = *(const float4*)&psgn[o + 64];
        const float p[8] = {p1l.x + acc[i][0], p1l.y + acc[i][1], p1l.z + acc[i][2], p1l.w + acc[i][3],
                            p1h.x + acc[i][4], p1h.y + acc[i][5], p1h.z + acc[i][6], p1h.w + acc[i][7]};
        *(float4*)&psgn[o]      = make_float4((p[0] >= 0.f) ? 1.f : -1.f, (p[1] >= 0.f) ? 1.f : -1.f,
                                              (p[2] >= 0.f) ? 1.f : -1.f, (p[3] >= 0.f) ? 1.f : -1.f);
        *(float4*)&psgn[o + 64] = make_float4((p[4] >= 0.f) ? 1.f : -1.f, (p[5] >= 0.f) ? 1.f : -1.f,
                                              (p[6] >= 0.f) ? 1.f : -1.f, (p[7] >= 0.f) ? 1.f : -1.f);
    }
}

// ---------------- KN: norms = sqrt(nrm2) ----------------
__global__ __launch_bounds__(256) void kN_sqrt(const double* __restrict__ nrm2, float* __restrict__ nrm)
{
    const int i = blockIdx.x * 256 + threadIdx.x;
    if (i < B_ROWS) nrm[i] = (float)sqrt(nrm2[i]);
}

extern "C" void kernel_launch(void* const* d_in, const int* in_sizes, int n_in,
                              void* d_out, int out_size, void* d_ws, size_t ws_size,
                              hipStream_t stream) {
    const float* X  = (const float*)d_in[0];
    const float* Pi = (const float*)d_in[1];
    const float* C  = (const float*)d_in[2];
    const float* S  = (const float*)d_in[3];

    float* out  = (float*)d_out;
    float* idxf = out;                                   // B*D (index values)
    float* sgn  = out + (size_t)B_ROWS * DIM;            // B*D (+-1); ALSO split-K partial scratch
    float* nrm  = sgn + (size_t)B_ROWS * DIM;            // B

    char* ws = (char*)d_ws;
    float*         R    = (float*)ws;                                          // 128 MiB
    unsigned char* idx8 = (unsigned char*)(ws + (size_t)B_ROWS * DIM * 4);     //  32 MiB
    double*        nrm2 = (double*)(ws + (size_t)B_ROWS * DIM * 5);            // 256 KiB

    hipMemsetAsync(nrm2, 0, (size_t)B_ROWS * sizeof(double), stream);

    dim3 blk(256);
    dim3 gG(DIM / 128, B_ROWS / 256);                    // 8 x 128 = 1024 blocks

    kT_part <<<gG, blk, 0, stream>>>(X, Pi, sgn);                    // p1 of y
    k1_final<<<gG, blk, 0, stream>>>(X, Pi, C, sgn, idxf, idx8);     // y, argmin
    k3_part <<<gG, blk, 0, stream>>>(idx8, Pi, C, sgn);              // p1 of xhat
    k3_final<<<gG, blk, 0, stream>>>(X, Pi, C, idx8, sgn, R, nrm2);  // R, norm partials
    kN_sqrt <<<dim3(B_ROWS / 256), blk, 0, stream>>>(nrm2, nrm);
    kT_part <<<gG, blk, 0, stream>>>(R, S, sgn);                     // p1 of P
    k5_final<<<gG, blk, 0, stream>>>(R, S, sgn);                     // signs (in place)
}

// Round 21
// 2737.860 us; speedup vs baseline: 1.9901x; 1.9901x over previous
//
#include <hip/hip_runtime.h>
#include <math.h>

#define B_ROWS 32768
#define DIM    1024
#define PAD    140             // stride ≡ 12 (mod 32); col' = col + 4*(row>>3) ≤ 139
#define LDSF   (2*2*32*PAD)    // 17920 floats = 71.7 KB (≥ 16384 exchange floats)

// Numerics contract (verified r10-r20, absmax 0.0): BLIS sgemm, KC=512.
// Per C element: p1 = serial ascending FMA chain k=0..511, p2 = k=512..1023,
// C = fl(p1+p2). Panels split across the two 256-thread halves of a
// 512-thread block; combined via LDS exchange at the end.
//
// FINAL CONFIGURATION (r18, best of r11-r20 sweep):
//  - 8x8 register tile, 128x128 block, 512 threads, panel-split (acc 32 regs
//    + 24-reg prefetch fragment -> VGPR 96-128 -> 4 waves/SIMD).
//  - Both-sides bank layout: stride 140 ≡ 12 mod 32, col' = col+4*(krow>>3):
//    writes <=2-way, A reads broadcast, B reads 2-way -> conflicts == 0 (measured).
//  - Register prefetch of chunk t+1 issued between barriers, hidden under compute.
//  - k4 (norms) fused into k3 epilogue; split-K partial tricks REJECTED
//    (r19: 16x8 tile -> 2 waves/SIMD, no gain; r20: + dbuf -> VGPR 256 spill, 2x slower).

struct FragT { float4 a0, a1, a2, a3, b0, b1, b2, b3; };

__device__ __forceinline__ void loadT(const float* pA, const float* pB, FragT& f) {
    f.a0 = *(const float4*)(pA);
    f.a1 = *(const float4*)(pA + (size_t)32 * DIM);
    f.a2 = *(const float4*)(pA + (size_t)64 * DIM);
    f.a3 = *(const float4*)(pA + (size_t)96 * DIM);
    f.b0 = *(const float4*)(pB);
    f.b1 = *(const float4*)(pB + (size_t)32 * DIM);
    f.b2 = *(const float4*)(pB + (size_t)64 * DIM);
    f.b3 = *(const float4*)(pB + (size_t)96 * DIM);
}

__device__ __forceinline__ void storeT(const FragT& f, float (*As)[PAD], float (*Bs)[PAD],
                                       int kq, int r0) {
    const int c0 = kq * 4;
    const int sh = 4 * (kq >> 1);          // = 4*((c0+j)>>3) for j<4
#pragma unroll
    for (int i = 0; i < 4; ++i) {
        const float4 v = (i == 0) ? f.a0 : (i == 1) ? f.a1 : (i == 2) ? f.a2 : f.a3;
        const int col = r0 + 32 * i + sh;
        As[c0 + 0][col] = v.x; As[c0 + 1][col] = v.y;
        As[c0 + 2][col] = v.z; As[c0 + 3][col] = v.w;
    }
#pragma unroll
    for (int i = 0; i < 4; ++i) {
        const float4 v = (i == 0) ? f.b0 : (i == 1) ? f.b1 : (i == 2) ? f.b2 : f.b3;
        const int col = r0 + 32 * i + sh;
        Bs[c0 + 0][col] = v.x; Bs[c0 + 1][col] = v.y;
        Bs[c0 + 2][col] = v.z; Bs[c0 + 3][col] = v.w;
    }
}

__device__ __forceinline__ void computeT(const float (*As)[PAD], const float (*Bs)[PAD],
                                         int tx, int ty, float (&acc)[8][8]) {
#pragma unroll
    for (int kk = 0; kk < 32; ++kk) {
        const int sh = 4 * (kk >> 3);      // compile-time const per unrolled kk
        const float4 a0 = *(const float4*)&As[kk][ty * 8 + sh];
        const float4 a1 = *(const float4*)&As[kk][ty * 8 + 4 + sh];
        const float4 b0 = *(const float4*)&Bs[kk][tx * 4 + sh];
        const float4 b1 = *(const float4*)&Bs[kk][tx * 4 + 64 + sh];
        const float a[8] = {a0.x, a0.y, a0.z, a0.w, a1.x, a1.y, a1.z, a1.w};
        const float b[8] = {b0.x, b0.y, b0.z, b0.w, b1.x, b1.y, b1.z, b1.w};
#pragma unroll
        for (int i = 0; i < 8; ++i)
#pragma unroll
            for (int j = 0; j < 8; ++j)
                acc[i][j] = fmaf(a[i], b[j], acc[i][j]);
    }
}

// ---------------- K1: y = X @ Pi^T ; argmin -> idxf + idx8 ----------------
__global__ __launch_bounds__(512) void k1_rot_quant(
    const float* __restrict__ X, const float* __restrict__ Pi, const float* __restrict__ C,
    float* __restrict__ idxf, unsigned char* __restrict__ idx8)
{
    __shared__ float lds[LDSF];
    const int tid = threadIdx.x, pan = tid >> 8, pt = tid & 255;
    float (*As)[PAD] = (float(*)[PAD])(lds + pan * 32 * PAD);
    float (*Bs)[PAD] = (float(*)[PAD])(lds + 2 * 32 * PAD + pan * 32 * PAD);
    const int tx = pt & 15, ty = pt >> 4;
    const int kq = pt & 7, r0 = pt >> 3;
    const int m0 = blockIdx.y * 128, n0 = blockIdx.x * 128;
    const float* pA = X  + (size_t)(m0 + r0) * DIM + pan * 512 + kq * 4;
    const float* pB = Pi + (size_t)(n0 + r0) * DIM + pan * 512 + kq * 4;
    float acc[8][8] = {};
    FragT f;
    loadT(pA, pB, f);
    for (int t = 0; t < 16; ++t) {
        __syncthreads();
        storeT(f, As, Bs, kq, r0);
        __syncthreads();
        if (t < 15) loadT(pA + (t + 1) * 32, pB + (t + 1) * 32, f);
        computeT(As, Bs, tx, ty, acc);
    }
    __syncthreads();
    if (pan == 1) {
#pragma unroll
        for (int i = 0; i < 8; ++i)
#pragma unroll
            for (int j = 0; j < 8; ++j)
                lds[(i * 8 + j) * 256 + pt] = acc[i][j];
    }
    __syncthreads();
    if (pan == 0) {
        float c8[8];
#pragma unroll
        for (int t = 0; t < 8; ++t) c8[t] = C[t];
#pragma unroll
        for (int i = 0; i < 8; ++i) {
            const size_t o = (size_t)(m0 + ty * 8 + i) * DIM + n0 + tx * 4;
            float fv[8]; unsigned char bv[8];
#pragma unroll
            for (int j = 0; j < 8; ++j) {
                const float y = acc[i][j] + lds[(i * 8 + j) * 256 + pt];   // fl(p1+p2)
                float best = fabsf(y - c8[0]); int bi = 0;
#pragma unroll
                for (int t2 = 1; t2 < 8; ++t2) {
                    const float d = fabsf(y - c8[t2]);
                    if (d < best) { best = d; bi = t2; }   // strict <: np first-min tie
                }
                fv[j] = (float)bi; bv[j] = (unsigned char)bi;
            }
            *(float4*)&idxf[o]      = make_float4(fv[0], fv[1], fv[2], fv[3]);
            *(float4*)&idxf[o + 64] = make_float4(fv[4], fv[5], fv[6], fv[7]);
            *(uchar4*)&idx8[o]      = make_uchar4(bv[0], bv[1], bv[2], bv[3]);
            *(uchar4*)&idx8[o + 64] = make_uchar4(bv[4], bv[5], bv[6], bv[7]);
        }
    }
}

// ---------------- K3: xhat = yhat @ Pi ; R = X - xhat ; fused norm partials ----------------
__global__ __launch_bounds__(512) void k3_unrot_residual(
    const float* __restrict__ X, const float* __restrict__ Pi, const float* __restrict__ C,
    const unsigned char* __restrict__ idx8, float* __restrict__ R, double* __restrict__ nrm2)
{
    __shared__ float lds[LDSF];
    __shared__ float clut[8];
    const int tid = threadIdx.x, pan = tid >> 8, pt = tid & 255;
    float (*As)[PAD] = (float(*)[PAD])(lds + pan * 32 * PAD);
    float (*Bs)[PAD] = (float(*)[PAD])(lds + 2 * 32 * PAD + pan * 32 * PAD);
    const int tx = pt & 15, ty = pt >> 4;
    const int kq = pt & 7, r0 = pt >> 3;
    const int nq = pt & 31, kr0 = pt >> 5;                 // B-staging map (32 k x 128 n)
    const int m0 = blockIdx.y * 128, n0 = blockIdx.x * 128;
    if (tid < 8) clut[tid] = C[tid];
    __syncthreads();
    const unsigned char* pA = idx8 + (size_t)(m0 + r0) * DIM + pan * 512 + kq * 4;
    const float*         pB = Pi + (size_t)(pan * 512 + kr0) * DIM + n0 + nq * 4;
    float acc[8][8] = {};
    uchar4 ka[4]; float4 kb[4];
#pragma unroll
    for (int i = 0; i < 4; ++i) ka[i] = *(const uchar4*)(pA + (size_t)(32 * i) * DIM);
#pragma unroll
    for (int i = 0; i < 4; ++i) kb[i] = *(const float4*)(pB + (size_t)(8 * i) * DIM);
    for (int t = 0; t < 16; ++t) {
        __syncthreads();
        {
            const int c0 = kq * 4;
            const int sh = 4 * (kq >> 1);
#pragma unroll
            for (int i = 0; i < 4; ++i) {
                const int col = r0 + 32 * i + sh;
                As[c0 + 0][col] = clut[ka[i].x]; As[c0 + 1][col] = clut[ka[i].y];
                As[c0 + 2][col] = clut[ka[i].z]; As[c0 + 3][col] = clut[ka[i].w];
            }
#pragma unroll
            for (int i = 0; i < 4; ++i)
                *(float4*)&Bs[kr0 + 8 * i][nq * 4 + 4 * i] = kb[i];   // col' = n + 4*(row>>3)
        }
        __syncthreads();
        if (t < 15) {
#pragma unroll
            for (int i = 0; i < 4; ++i)
                ka[i] = *(const uchar4*)(pA + (t + 1) * 32 + (size_t)(32 * i) * DIM);
#pragma unroll
            for (int i = 0; i < 4; ++i)
                kb[i] = *(const float4*)(pB + (size_t)((t + 1) * 32 + 8 * i) * DIM);
        }
        computeT(As, Bs, tx, ty, acc);
    }
    __syncthreads();
    if (pan == 1) {
#pragma unroll
        for (int i = 0; i < 8; ++i)
#pragma unroll
            for (int j = 0; j < 8; ++j)
                lds[(i * 8 + j) * 256 + pt] = acc[i][j];
    }
    __syncthreads();
    if (pan == 0) {
#pragma unroll
        for (int i = 0; i < 8; ++i) {
            const int row = m0 + ty * 8 + i;
            const size_t o = (size_t)row * DIM + n0 + tx * 4;
            const float4 x0 = *(const float4*)&X[o];
            const float4 x1 = *(const float4*)&X[o + 64];
            float rv[8];
            rv[0] = x0.x - (acc[i][0] + lds[(i * 8 + 0) * 256 + pt]);
            rv[1] = x0.y - (acc[i][1] + lds[(i * 8 + 1) * 256 + pt]);
            rv[2] = x0.z - (acc[i][2] + lds[(i * 8 + 2) * 256 + pt]);
            rv[3] = x0.w - (acc[i][3] + lds[(i * 8 + 3) * 256 + pt]);
            rv[4] = x1.x - (acc[i][4] + lds[(i * 8 + 4) * 256 + pt]);
            rv[5] = x1.y - (acc[i][5] + lds[(i * 8 + 5) * 256 + pt]);
            rv[6] = x1.z - (acc[i][6] + lds[(i * 8 + 6) * 256 + pt]);
            rv[7] = x1.w - (acc[i][7] + lds[(i * 8 + 7) * 256 + pt]);
            *(float4*)&R[o]      = make_float4(rv[0], rv[1], rv[2], rv[3]);
            *(float4*)&R[o + 64] = make_float4(rv[4], rv[5], rv[6], rv[7]);
            double s = 0.0;
#pragma unroll
            for (int j = 0; j < 8; ++j) s = fma((double)rv[j], (double)rv[j], s);
#pragma unroll
            for (int mask = 1; mask < 16; mask <<= 1) s += __shfl_xor(s, mask, 16);
            if (tx == 0) atomicAdd(&nrm2[row], s);
        }
    }
}

// ---------------- K5: P = R @ S^T ; sign ----------------
__global__ __launch_bounds__(512) void k5_qjl(
    const float* __restrict__ R, const float* __restrict__ S, float* __restrict__ sgn)
{
    __shared__ float lds[LDSF];
    const int tid = threadIdx.x, pan = tid >> 8, pt = tid & 255;
    float (*As)[PAD] = (float(*)[PAD])(lds + pan * 32 * PAD);
    float (*Bs)[PAD] = (float(*)[PAD])(lds + 2 * 32 * PAD + pan * 32 * PAD);
    const int tx = pt & 15, ty = pt >> 4;
    const int kq = pt & 7, r0 = pt >> 3;
    const int m0 = blockIdx.y * 128, n0 = blockIdx.x * 128;
    const float* pA = R + (size_t)(m0 + r0) * DIM + pan * 512 + kq * 4;
    const float* pB = S + (size_t)(n0 + r0) * DIM + pan * 512 + kq * 4;
    float acc[8][8] = {};
    FragT f;
    loadT(pA, pB, f);
    for (int t = 0; t < 16; ++t) {
        __syncthreads();
        storeT(f, As, Bs, kq, r0);
        __syncthreads();
        if (t < 15) loadT(pA + (t + 1) * 32, pB + (t + 1) * 32, f);
        computeT(As, Bs, tx, ty, acc);
    }
    __syncthreads();
    if (pan == 1) {
#pragma unroll
        for (int i = 0; i < 8; ++i)
#pragma unroll
            for (int j = 0; j < 8; ++j)
                lds[(i * 8 + j) * 256 + pt] = acc[i][j];
    }
    __syncthreads();
    if (pan == 0) {
#pragma unroll
        for (int i = 0; i < 8; ++i) {
            const size_t o = (size_t)(m0 + ty * 8 + i) * DIM + n0 + tx * 4;
            float pv[8];
#pragma unroll
            for (int j = 0; j < 8; ++j) pv[j] = acc[i][j] + lds[(i * 8 + j) * 256 + pt];
            *(float4*)&sgn[o]      = make_float4((pv[0] >= 0.f) ? 1.f : -1.f, (pv[1] >= 0.f) ? 1.f : -1.f,
                                                 (pv[2] >= 0.f) ? 1.f : -1.f, (pv[3] >= 0.f) ? 1.f : -1.f);
            *(float4*)&sgn[o + 64] = make_float4((pv[4] >= 0.f) ? 1.f : -1.f, (pv[5] >= 0.f) ? 1.f : -1.f,
                                                 (pv[6] >= 0.f) ? 1.f : -1.f, (pv[7] >= 0.f) ? 1.f : -1.f);
        }
    }
}

// ---------------- KN: norms = sqrt(nrm2) ----------------
__global__ __launch_bounds__(256) void kN_sqrt(const double* __restrict__ nrm2, float* __restrict__ nrm)
{
    const int i = blockIdx.x * 256 + threadIdx.x;
    if (i < B_ROWS) nrm[i] = (float)sqrt(nrm2[i]);
}

extern "C" void kernel_launch(void* const* d_in, const int* in_sizes, int n_in,
                              void* d_out, int out_size, void* d_ws, size_t ws_size,
                              hipStream_t stream) {
    const float* X  = (const float*)d_in[0];
    const float* Pi = (const float*)d_in[1];
    const float* C  = (const float*)d_in[2];
    const float* S  = (const float*)d_in[3];

    float* out  = (float*)d_out;
    float* idxf = out;                                   // B*D (index values)
    float* sgn  = out + (size_t)B_ROWS * DIM;            // B*D (+-1)
    float* nrm  = sgn + (size_t)B_ROWS * DIM;            // B

    char* ws = (char*)d_ws;
    float*         R    = (float*)ws;                                          // 128 MiB
    unsigned char* idx8 = (unsigned char*)(ws + (size_t)B_ROWS * DIM * 4);     //  32 MiB
    double*        nrm2 = (double*)(ws + (size_t)B_ROWS * DIM * 5);            // 256 KiB

    hipMemsetAsync(nrm2, 0, (size_t)B_ROWS * sizeof(double), stream);

    dim3 blk(512);
    dim3 gG(DIM / 128, B_ROWS / 128);                    // 8 x 256 = 2048 blocks

    k1_rot_quant     <<<gG, blk, 0, stream>>>(X, Pi, C, idxf, idx8);
    k3_unrot_residual<<<gG, blk, 0, stream>>>(X, Pi, C, idx8, R, nrm2);
    kN_sqrt          <<<dim3(B_ROWS / 256), dim3(256), 0, stream>>>(nrm2, nrm);
    k5_qjl           <<<gG, blk, 0, stream>>>(R, S, sgn);
}